// Round 1
// baseline (401.744 us; speedup 1.0000x reference)
//
#include <hip/hip_runtime.h>

// ---------------------------------------------------------------------------
// Kernel 1: camera[b] = sum_c W[c] * x[b,c,:,:]
// One wave (64 lanes) per batch element b. Lane l owns matrices c = 4l..4l+3,
// i.e. 36 consecutive floats = 9 aligned float4s. The (c_offset, j) mapping of
// each float4 component is static, so we accumulate into 9 register
// accumulators with no dynamic indexing. Then a 64-lane xor-butterfly reduce,
// and lanes 0..8 store the 9 camera entries.
// ---------------------------------------------------------------------------
__global__ __launch_bounds__(256) void camera_reduce_kernel(
    const float* __restrict__ x, const float* __restrict__ W,
    float* __restrict__ cam, int B)
{
    const int wave = threadIdx.x >> 6;
    const int lane = threadIdx.x & 63;
    const int b = blockIdx.x * 4 + wave;
    if (b >= B) return;

    // lane base: b*2304 + lane*36 floats; 144-byte stride -> 16B aligned.
    const float4* xv = reinterpret_cast<const float4*>(
        x + (size_t)b * 2304 + (size_t)lane * 36);
    const float4 wv = reinterpret_cast<const float4*>(W)[lane];

    float a0 = 0.f, a1 = 0.f, a2 = 0.f, a3 = 0.f, a4 = 0.f,
          a5 = 0.f, a6 = 0.f, a7 = 0.f, a8 = 0.f;
    float4 v;
    v = xv[0]; a0 += v.x*wv.x; a1 += v.y*wv.x; a2 += v.z*wv.x; a3 += v.w*wv.x;
    v = xv[1]; a4 += v.x*wv.x; a5 += v.y*wv.x; a6 += v.z*wv.x; a7 += v.w*wv.x;
    v = xv[2]; a8 += v.x*wv.x; a0 += v.y*wv.y; a1 += v.z*wv.y; a2 += v.w*wv.y;
    v = xv[3]; a3 += v.x*wv.y; a4 += v.y*wv.y; a5 += v.z*wv.y; a6 += v.w*wv.y;
    v = xv[4]; a7 += v.x*wv.y; a8 += v.y*wv.y; a0 += v.z*wv.z; a1 += v.w*wv.z;
    v = xv[5]; a2 += v.x*wv.z; a3 += v.y*wv.z; a4 += v.z*wv.z; a5 += v.w*wv.z;
    v = xv[6]; a6 += v.x*wv.z; a7 += v.y*wv.z; a8 += v.z*wv.z; a0 += v.w*wv.w;
    v = xv[7]; a1 += v.x*wv.w; a2 += v.y*wv.w; a3 += v.z*wv.w; a4 += v.w*wv.w;
    v = xv[8]; a5 += v.x*wv.w; a6 += v.y*wv.w; a7 += v.z*wv.w; a8 += v.w*wv.w;

    // 64-lane xor butterfly: every lane ends with the full sums.
    #pragma unroll
    for (int m = 32; m >= 1; m >>= 1) {
        a0 += __shfl_xor(a0, m, 64);
        a1 += __shfl_xor(a1, m, 64);
        a2 += __shfl_xor(a2, m, 64);
        a3 += __shfl_xor(a3, m, 64);
        a4 += __shfl_xor(a4, m, 64);
        a5 += __shfl_xor(a5, m, 64);
        a6 += __shfl_xor(a6, m, 64);
        a7 += __shfl_xor(a7, m, 64);
        a8 += __shfl_xor(a8, m, 64);
    }

    if (lane < 9) {
        float r = (lane == 0) ? a0 : (lane == 1) ? a1 : (lane == 2) ? a2 :
                  (lane == 3) ? a3 : (lane == 4) ? a4 : (lane == 5) ? a5 :
                  (lane == 6) ? a6 : (lane == 7) ? a7 : a8;
        cam[(size_t)b * 9 + lane] = r;
    }
}

// ---------------------------------------------------------------------------
// Kernel 2: in-place projection of each 3x3 matrix onto SO(3).
// Wahba/Horn: R* = argmax_{R in SO(3)} tr(R^T M) = top eigenvector (as a
// quaternion) of the 4x4 symmetric matrix N(M). Cyclic Jacobi, 5 sweeps.
// Identical to the reference's U diag(1,1,det(UV^T)) V^T (descending svals).
// ---------------------------------------------------------------------------
#define JROT(P, Q)                                                         \
  do {                                                                     \
    float apq = A[P][Q];                                                   \
    if (fabsf(apq) > 1e-20f) {                                             \
      float app = A[P][P], aqq = A[Q][Q];                                  \
      float tau = (aqq - app) / (2.0f * apq);                              \
      float tt = copysignf(1.0f, tau) /                                    \
                 (fabsf(tau) + sqrtf(tau * tau + 1.0f));                   \
      float c = rsqrtf(tt * tt + 1.0f);                                    \
      float s = tt * c;                                                    \
      _Pragma("unroll") for (int k = 0; k < 4; ++k) {                      \
        float t1 = A[k][P], t2 = A[k][Q];                                  \
        A[k][P] = c * t1 - s * t2;                                         \
        A[k][Q] = s * t1 + c * t2;                                         \
      }                                                                    \
      _Pragma("unroll") for (int k = 0; k < 4; ++k) {                      \
        float t1 = A[P][k], t2 = A[Q][k];                                  \
        A[P][k] = c * t1 - s * t2;                                         \
        A[Q][k] = s * t1 + c * t2;                                         \
      }                                                                    \
      _Pragma("unroll") for (int k = 0; k < 4; ++k) {                      \
        float t1 = V[k][P], t2 = V[k][Q];                                  \
        V[k][P] = c * t1 - s * t2;                                         \
        V[k][Q] = s * t1 + c * t2;                                         \
      }                                                                    \
    }                                                                      \
  } while (0)

__global__ __launch_bounds__(256) void polar_so3_kernel(float* __restrict__ io,
                                                        int B)
{
    const int t = blockIdx.x * blockDim.x + threadIdx.x;
    if (t >= B) return;
    float* p = io + (size_t)t * 9;
    const float m00 = p[0], m01 = p[1], m02 = p[2];
    const float m10 = p[3], m11 = p[4], m12 = p[5];
    const float m20 = p[6], m21 = p[7], m22 = p[8];

    // N such that tr(R(q)^T M) = q^T N q, q = (w,x,y,z).
    float A[4][4];
    A[0][0] = m00 + m11 + m22;
    A[1][1] = m00 - m11 - m22;
    A[2][2] = m11 - m00 - m22;
    A[3][3] = m22 - m00 - m11;
    A[0][1] = A[1][0] = m21 - m12;
    A[0][2] = A[2][0] = m02 - m20;
    A[0][3] = A[3][0] = m10 - m01;
    A[1][2] = A[2][1] = m01 + m10;
    A[1][3] = A[3][1] = m02 + m20;
    A[2][3] = A[3][2] = m12 + m21;

    float V[4][4] = {{1.f, 0.f, 0.f, 0.f},
                     {0.f, 1.f, 0.f, 0.f},
                     {0.f, 0.f, 1.f, 0.f},
                     {0.f, 0.f, 0.f, 1.f}};

    #pragma unroll
    for (int sweep = 0; sweep < 5; ++sweep) {
        JROT(0, 1); JROT(0, 2); JROT(0, 3);
        JROT(1, 2); JROT(1, 3); JROT(2, 3);
    }

    // argmax eigenvalue (diagonal of A), select that column of V (static idx).
    int best = 0;
    float bd = A[0][0];
    if (A[1][1] > bd) { bd = A[1][1]; best = 1; }
    if (A[2][2] > bd) { bd = A[2][2]; best = 2; }
    if (A[3][3] > bd) { bd = A[3][3]; best = 3; }
    float qw = (best == 0) ? V[0][0] : (best == 1) ? V[0][1] : (best == 2) ? V[0][2] : V[0][3];
    float qx = (best == 0) ? V[1][0] : (best == 1) ? V[1][1] : (best == 2) ? V[1][2] : V[1][3];
    float qy = (best == 0) ? V[2][0] : (best == 1) ? V[2][1] : (best == 2) ? V[2][2] : V[2][3];
    float qz = (best == 0) ? V[3][0] : (best == 1) ? V[3][1] : (best == 2) ? V[3][2] : V[3][3];

    const float nrm = rsqrtf(qw * qw + qx * qx + qy * qy + qz * qz);
    qw *= nrm; qx *= nrm; qy *= nrm; qz *= nrm;

    const float xx = qx * qx, yy = qy * qy, zz = qz * qz;
    const float xy = qx * qy, xz = qx * qz, yz = qy * qz;
    const float wx = qw * qx, wy = qw * qy, wz = qw * qz;

    p[0] = 1.0f - 2.0f * (yy + zz);
    p[1] = 2.0f * (xy - wz);
    p[2] = 2.0f * (xz + wy);
    p[3] = 2.0f * (xy + wz);
    p[4] = 1.0f - 2.0f * (xx + zz);
    p[5] = 2.0f * (yz - wx);
    p[6] = 2.0f * (yz + wx) * 0.0f + 2.0f * (xz - wy);  // R20 = 2(xz - wy)
    p[7] = 2.0f * (yz + wx);
    p[8] = 1.0f - 2.0f * (xx + yy);
}

extern "C" void kernel_launch(void* const* d_in, const int* in_sizes, int n_in,
                              void* d_out, int out_size, void* d_ws, size_t ws_size,
                              hipStream_t stream)
{
    const float* x = (const float*)d_in[0];
    const float* W = (const float*)d_in[1];
    float* out = (float*)d_out;

    const int C = in_sizes[1];           // 256
    const int B = in_sizes[0] / (C * 9); // 32768

    // Phase 1: camera matrices -> d_out (exactly out_size floats).
    camera_reduce_kernel<<<(B + 3) / 4, 256, 0, stream>>>(x, W, out, B);
    // Phase 2: in-place SO(3) projection.
    polar_so3_kernel<<<(B + 255) / 256, 256, 0, stream>>>(out, B);
}